// Round 1
// baseline (4674.811 us; speedup 1.0000x reference)
//
#include <hip/hip_runtime.h>
#include <math.h>

#define NITEMS 50000
#define NROWS 50001
#define DD 512
#define HH 512
#define TT 16
#define NEGV (-1e18f)

// ---- order-preserving float <-> uint key (for exact, associative atomic max) ----
__device__ __forceinline__ unsigned fkey(float f) {
  unsigned u = __float_as_uint(f);
  return (u & 0x80000000u) ? ~u : (u | 0x80000000u);
}
__device__ __forceinline__ float fkey_inv(unsigned k) {
  return __uint_as_float((k & 0x80000000u) ? (k ^ 0x80000000u) : ~k);
}

// ---------------- init state ----------------
__global__ void k_init(int* __restrict__ sel, float* __restrict__ x, float* __restrict__ h,
                       float* __restrict__ c, int* __restrict__ done,
                       const float* __restrict__ init_i, const float* __restrict__ init_h,
                       const float* __restrict__ init_c) {
  int i = blockIdx.x * blockDim.x + threadIdx.x;
  if (i < NROWS) sel[i] = 0;
  if (i < HH) { x[i] = init_i[i]; h[i] = init_h[i]; c[i] = init_c[i]; }
  if (i == 0) *done = 0;
}

// ---------------- feat = mem @ W  (mem row 50000 == stop) ----------------
// 128x128 tile, BK=8, 256 threads, 8x8 microtile, fp32
__launch_bounds__(256)
__global__ void k_feat_gemm(const float* __restrict__ A0, const float* __restrict__ stoprow,
                            const float* __restrict__ B, float* __restrict__ C) {
  __shared__ float As[8][128];
  __shared__ float Bs[8][128];
  const int tid = threadIdx.x;
  const int m0 = blockIdx.x * 128, n0 = blockIdx.y * 128;
  const int tx = tid & 15, ty = tid >> 4;
  const int ar = tid >> 1, ak = (tid & 1) * 4;
  const int bk = tid >> 5, bc = (tid & 31) * 4;
  const int arow = m0 + ar;
  const float* Arow = (arow < NITEMS) ? (A0 + (size_t)arow * DD) : stoprow;
  const bool avalid = (arow < NROWS);
  float acc[8][8];
#pragma unroll
  for (int i = 0; i < 8; ++i)
#pragma unroll
    for (int j = 0; j < 8; ++j) acc[i][j] = 0.f;

  for (int kt = 0; kt < DD; kt += 8) {
    float4 av = avalid ? *(const float4*)(Arow + kt + ak) : make_float4(0.f, 0.f, 0.f, 0.f);
    As[ak + 0][ar] = av.x;
    As[ak + 1][ar] = av.y;
    As[ak + 2][ar] = av.z;
    As[ak + 3][ar] = av.w;
    *(float4*)&Bs[bk][bc] = *(const float4*)(B + (size_t)(kt + bk) * HH + n0 + bc);
    __syncthreads();
#pragma unroll
    for (int k = 0; k < 8; ++k) {
      float a[8], b[8];
      *(float4*)&a[0] = *(const float4*)&As[k][ty * 8];
      *(float4*)&a[4] = *(const float4*)&As[k][ty * 8 + 4];
      *(float4*)&b[0] = *(const float4*)&Bs[k][tx * 8];
      *(float4*)&b[4] = *(const float4*)&Bs[k][tx * 8 + 4];
#pragma unroll
      for (int i = 0; i < 8; ++i)
#pragma unroll
        for (int j = 0; j < 8; ++j) acc[i][j] = fmaf(a[i], b[j], acc[i][j]);
    }
    __syncthreads();
  }
#pragma unroll
  for (int i = 0; i < 8; ++i) {
    int row = m0 + ty * 8 + i;
    if (row < NROWS) {
      float* crow = C + (size_t)row * HH + n0 + tx * 8;
      *(float4*)crow = make_float4(acc[i][0], acc[i][1], acc[i][2], acc[i][3]);
      *(float4*)(crow + 4) = make_float4(acc[i][4], acc[i][5], acc[i][6], acc[i][7]);
    }
  }
}

// ---------------- LSTM gates: gates[r] = x.wih[r] + h.whh[r] + bih[r] + bhh[r] ----------------
__launch_bounds__(256)
__global__ void k_lstm_gates(const float* __restrict__ x, const float* __restrict__ h,
                             const float* __restrict__ w_ih, const float* __restrict__ w_hh,
                             const float* __restrict__ b_ih, const float* __restrict__ b_hh,
                             float* __restrict__ gates) {
  const int tid = threadIdx.x;
  const int lane = tid & 63;
  const int r = blockIdx.x * 4 + (tid >> 6);  // 512 blocks * 4 waves = 2048 rows
  const float4* wi = (const float4*)(w_ih + (size_t)r * DD);
  const float4* wh = (const float4*)(w_hh + (size_t)r * DD);
  const float4* x4 = (const float4*)x;
  const float4* h4 = (const float4*)h;
  float s = 0.f;
  float4 a, w;
  a = x4[lane * 2];     w = wi[lane * 2];     s += a.x * w.x + a.y * w.y + a.z * w.z + a.w * w.w;
  a = x4[lane * 2 + 1]; w = wi[lane * 2 + 1]; s += a.x * w.x + a.y * w.y + a.z * w.z + a.w * w.w;
  a = h4[lane * 2];     w = wh[lane * 2];     s += a.x * w.x + a.y * w.y + a.z * w.z + a.w * w.w;
  a = h4[lane * 2 + 1]; w = wh[lane * 2 + 1]; s += a.x * w.x + a.y * w.y + a.z * w.z + a.w * w.w;
#pragma unroll
  for (int off = 32; off > 0; off >>= 1) s += __shfl_xor(s, off);
  if (lane == 0) gates[r] = s + b_ih[r] + b_hh[r];
}

// ---------------- LSTM elementwise; also zeroes hop max accumulator ----------------
__launch_bounds__(512)
__global__ void k_lstm_combine(const float* __restrict__ gates, float* __restrict__ h,
                               float* __restrict__ c, unsigned* __restrict__ smaxkey) {
  const int tid = threadIdx.x;
  float gi = gates[tid], gf = gates[HH + tid], gg = gates[2 * HH + tid], go = gates[3 * HH + tid];
  float si = 1.f / (1.f + expf(-gi));
  float sf = 1.f / (1.f + expf(-gf));
  float so = 1.f / (1.f + expf(-go));
  float cn = sf * c[tid] + si * tanhf(gg);
  c[tid] = cn;
  h[tid] = so * tanhf(cn);
  if (tid == 0) *smaxkey = 0u;
}

// ---------------- b[j] = sum_i q[i] * W[i][j]   (q @ W) ----------------
__launch_bounds__(256)
__global__ void k_gemv(const float* __restrict__ q, const float* __restrict__ W,
                       float* __restrict__ out) {
  __shared__ float lds[256];
  const int tid = threadIdx.x;
  const int c = tid & 63, rs = tid >> 6;
  const int j = blockIdx.x * 64 + c;
  float p = 0.f;
  for (int i = rs * 128; i < rs * 128 + 128; ++i) p += q[i] * W[(size_t)i * HH + j];
  lds[tid] = p;
  __syncthreads();
  if (tid < 64) out[blockIdx.x * 64 + tid] = lds[tid] + lds[tid + 64] + lds[tid + 128] + lds[tid + 192];
}

// ---------------- scores: s[m] = sum_h tanh(feat[m,h]+b[h])*v[h]; optional mask / argmax(s+g) ----------------
__launch_bounds__(256)
__global__ void k_score(const float* __restrict__ feat, const float* __restrict__ bvec,
                        const float* __restrict__ v, float* __restrict__ sout,
                        unsigned* __restrict__ maxkey, const int* __restrict__ sel,
                        const float* __restrict__ gum, unsigned long long* __restrict__ amaxkey) {
  const int tid = threadIdx.x;
  const int lane = tid & 63;
  const int wv = (blockIdx.x * 256 + tid) >> 6;  // 2048 waves
  float bv[8], vv[8];
#pragma unroll
  for (int j = 0; j < 8; ++j) { bv[j] = bvec[lane * 8 + j]; vv[j] = v[lane * 8 + j]; }
  float lmax = -3.0e38f;
  float bestv = -3.0e38f;
  int besti = 0;
  for (int m = wv; m < NROWS; m += 2048) {
    float s;
    if (sel != nullptr && sel[m]) {
      s = NEGV;
    } else {
      const float4* fp = (const float4*)(feat + (size_t)m * HH);
      float4 A = fp[lane * 2], B = fp[lane * 2 + 1];
      s  = tanhf(A.x + bv[0]) * vv[0];
      s += tanhf(A.y + bv[1]) * vv[1];
      s += tanhf(A.z + bv[2]) * vv[2];
      s += tanhf(A.w + bv[3]) * vv[3];
      s += tanhf(B.x + bv[4]) * vv[4];
      s += tanhf(B.y + bv[5]) * vv[5];
      s += tanhf(B.z + bv[6]) * vv[6];
      s += tanhf(B.w + bv[7]) * vv[7];
#pragma unroll
      for (int off = 32; off > 0; off >>= 1) s += __shfl_xor(s, off);
    }
    if (lane == 0) sout[m] = s;
    lmax = fmaxf(lmax, s);
    if (gum != nullptr) {
      float sv = s + gum[m];
      if (sv > bestv) { bestv = sv; besti = m; }
    }
  }
  __shared__ float wmax[4];
  __shared__ unsigned long long wkey[4];
  const int w = tid >> 6;
  if (lane == 0) {
    wmax[w] = lmax;
    if (gum != nullptr)
      wkey[w] = ((unsigned long long)fkey(bestv) << 32) | (unsigned)(NITEMS - besti);
  }
  __syncthreads();
  if (tid == 0) {
    float m4 = fmaxf(fmaxf(wmax[0], wmax[1]), fmaxf(wmax[2], wmax[3]));
    atomicMax(maxkey, fkey(m4));
    if (gum != nullptr) {
      unsigned long long k4 = max(max(wkey[0], wkey[1]), max(wkey[2], wkey[3]));
      atomicMax(amaxkey, k4);
    }
  }
}

// ---------------- hop softmax-weighted sum, deterministic partials ----------------
__launch_bounds__(512)
__global__ void k_hop_accum(const float* __restrict__ s, const unsigned* __restrict__ smaxkey,
                            const float* __restrict__ feat, float* __restrict__ qp,
                            float* __restrict__ Zp) {
  const int tid = threadIdx.x;
  const int b = blockIdx.x;  // 256 blocks
  const float smax = fkey_inv(*smaxkey);
  float acc = 0.f, zacc = 0.f;
  for (int m = b; m < NROWS; m += 256) {
    float e = expf(s[m] - smax);
    acc += e * feat[(size_t)m * HH + tid];
    zacc += e;
  }
  qp[b * HH + tid] = acc;
  if (tid == 0) Zp[b] = zacc;
}

// ---------------- finalize hop glimpse: qn = (sum qp)/Z ; zero attn accumulators ----------------
__launch_bounds__(512)
__global__ void k_hop_final(const float* __restrict__ qp, const float* __restrict__ Zp,
                            float* __restrict__ qn, unsigned* __restrict__ Mkey,
                            unsigned long long* __restrict__ amaxkey) {
  __shared__ float red[512];
  const int tid = threadIdx.x;
  red[tid] = (tid < 256) ? Zp[tid] : 0.f;
  __syncthreads();
  for (int s2 = 256; s2 > 0; s2 >>= 1) {
    if (tid < s2) red[tid] += red[tid + s2];
    __syncthreads();
  }
  const float Z = red[0];
  float q = 0.f;
  for (int b = 0; b < 256; ++b) q += qp[b * HH + tid];
  qn[tid] = q / Z;
  if (tid == 0) { *Mkey = 0u; *amaxkey = 0ull; }
}

// ---------------- attn partition function partials (deterministic) ----------------
__launch_bounds__(256)
__global__ void k_attn_Z(const float* __restrict__ sc, const unsigned* __restrict__ Mkey,
                         float* __restrict__ Zp2) {
  const int b = blockIdx.x, tid = threadIdx.x;  // 64 blocks
  const float M = fkey_inv(*Mkey);
  float z = 0.f;
  for (int m = b * 256 + tid; m < NROWS; m += 64 * 256) z += expf(sc[m] - M);
  __shared__ float red[256];
  red[tid] = z;
  __syncthreads();
  for (int s2 = 128; s2 > 0; s2 >>= 1) {
    if (tid < s2) red[tid] += red[tid + s2];
    __syncthreads();
  }
  if (tid == 0) Zp2[b] = red[0];
}

// ---------------- sample + bookkeeping + outputs ----------------
__launch_bounds__(512)
__global__ void k_step_final(const float* __restrict__ sc, const float* __restrict__ Zp2,
                             const unsigned* __restrict__ Mkey,
                             const unsigned long long* __restrict__ amaxkey,
                             int* __restrict__ sel, int* __restrict__ done, float* __restrict__ x,
                             const float* __restrict__ attn_mem, const float* __restrict__ stoprow,
                             float* __restrict__ outbuf, int t) {
  __shared__ float redz;
  __shared__ int s_out, s_copy;
  const int tid = threadIdx.x;
  if (tid < 64) {
    float z = Zp2[tid];
#pragma unroll
    for (int off = 32; off > 0; off >>= 1) z += __shfl_xor(z, off);
    if (tid == 0) redz = z;
  }
  __syncthreads();
  if (tid == 0) {
    float Z = redz;
    unsigned long long key = *amaxkey;
    int out = NITEMS - (int)(unsigned)(key & 0xFFFFFFFFull);
    float M = fkey_inv(*Mkey);
    int dn = *done;
    float lp = dn ? 0.f : (sc[out] - M - logf(Z));
    int orec = dn ? NITEMS : out;
    if (!dn) sel[out] = 1;
    int nd = dn || (out == NITEMS);
    *done = nd;
    outbuf[t] = (float)orec;
    outbuf[TT + t] = lp;
    s_out = out;
    s_copy = !nd;
  }
  __syncthreads();
  if (s_copy) x[tid] = (s_out < NITEMS) ? attn_mem[(size_t)s_out * DD + tid] : stoprow[tid];
}

// ======================================================================
extern "C" void kernel_launch(void* const* d_in, const int* in_sizes, int n_in,
                              void* d_out, int out_size, void* d_ws, size_t ws_size,
                              hipStream_t stream) {
  const float* attn_mem = (const float*)d_in[0];
  const float* stoprow  = (const float*)d_in[1];
  const float* init_h   = (const float*)d_in[2];
  const float* init_c   = (const float*)d_in[3];
  const float* init_i   = (const float*)d_in[4];
  const float* attn_wm  = (const float*)d_in[5];
  const float* attn_wq  = (const float*)d_in[6];
  const float* attn_v   = (const float*)d_in[7];
  const float* hop_wm   = (const float*)d_in[8];
  const float* hop_wq   = (const float*)d_in[9];
  const float* hop_v    = (const float*)d_in[10];
  const float* w_ih     = (const float*)d_in[11];
  const float* w_hh     = (const float*)d_in[12];
  const float* b_ih     = (const float*)d_in[13];
  const float* b_hh     = (const float*)d_in[14];
  const float* gumbel   = (const float*)d_in[15];

  float* ws = (float*)d_ws;
  size_t fo = 0;
  const size_t F = (size_t)NROWS * HH;  // 25,600,512
  float* attn_feat = ws + fo; fo += F;
  float* hop_feat  = ws + fo; fo += F;
  float* s_hop = ws + fo; fo += 50008;
  float* sc    = ws + fo; fo += 50008;
  int*   sel   = (int*)(ws + fo); fo += 50008;
  float* qp    = ws + fo; fo += 256 * HH;
  float* Zp    = ws + fo; fo += 256;
  float* Zp2   = ws + fo; fo += 64;
  float* gates = ws + fo; fo += 4 * HH;
  float* xv = ws + fo; fo += HH;
  float* hv = ws + fo; fo += HH;
  float* cv = ws + fo; fo += HH;
  float* qn = ws + fo; fo += HH;
  float* b1 = ws + fo; fo += HH;
  float* b2 = ws + fo; fo += HH;
  unsigned long long* amaxkey = (unsigned long long*)(ws + fo); fo += 2;
  unsigned* smaxkey = (unsigned*)(ws + fo); fo += 2;
  unsigned* Mkey    = (unsigned*)(ws + fo); fo += 2;
  int* done         = (int*)(ws + fo); fo += 2;
  if (fo * sizeof(float) > ws_size) return;  // workspace too small: fail loudly via unwritten d_out

  float* outf = (float*)d_out;

  k_init<<<(NROWS + 255) / 256, 256, 0, stream>>>(sel, xv, hv, cv, done, init_i, init_h, init_c);

  dim3 ggrid((NROWS + 127) / 128, 4);
  k_feat_gemm<<<ggrid, 256, 0, stream>>>(attn_mem, stoprow, attn_wm, attn_feat);
  k_feat_gemm<<<ggrid, 256, 0, stream>>>(attn_mem, stoprow, hop_wm, hop_feat);

  for (int t = 0; t < TT; ++t) {
    k_lstm_gates<<<512, 256, 0, stream>>>(xv, hv, w_ih, w_hh, b_ih, b_hh, gates);
    k_lstm_combine<<<1, 512, 0, stream>>>(gates, hv, cv, smaxkey);
    k_gemv<<<8, 256, 0, stream>>>(hv, hop_wq, b1);
    k_score<<<512, 256, 0, stream>>>(hop_feat, b1, hop_v, s_hop, smaxkey, nullptr, nullptr, nullptr);
    k_hop_accum<<<256, 512, 0, stream>>>(s_hop, smaxkey, hop_feat, qp, Zp);
    k_hop_final<<<1, 512, 0, stream>>>(qp, Zp, qn, Mkey, amaxkey);
    k_gemv<<<8, 256, 0, stream>>>(qn, attn_wq, b2);
    k_score<<<512, 256, 0, stream>>>(attn_feat, b2, attn_v, sc, Mkey, sel,
                                     gumbel + (size_t)t * NROWS, amaxkey);
    k_attn_Z<<<64, 256, 0, stream>>>(sc, Mkey, Zp2);
    k_step_final<<<1, 512, 0, stream>>>(sc, Zp2, Mkey, amaxkey, sel, done, xv,
                                        attn_mem, stoprow, outf, t);
  }
}

// Round 2
// 4000.494 us; speedup vs baseline: 1.1686x; 1.1686x over previous
//
#include <hip/hip_runtime.h>
#include <math.h>

#define NITEMS 50000
#define NROWS 50001
#define DD 512
#define HH 512
#define TT 16
#define NEGV (-1e18f)

// ---- order-preserving float <-> uint key ----
__device__ __forceinline__ unsigned fkey(float f) {
  unsigned u = __float_as_uint(f);
  return (u & 0x80000000u) ? ~u : (u | 0x80000000u);
}

// ---------------- init state ----------------
__global__ void k_init(int* __restrict__ sel, float* __restrict__ x, float* __restrict__ h,
                       float* __restrict__ c, int* __restrict__ done,
                       const float* __restrict__ init_i, const float* __restrict__ init_h,
                       const float* __restrict__ init_c) {
  int i = blockIdx.x * blockDim.x + threadIdx.x;
  if (i < NROWS) sel[i] = 0;
  if (i < HH) { x[i] = init_i[i]; h[i] = init_h[i]; c[i] = init_c[i]; }
  if (i == 0) *done = 0;
}

// ---------------- feat = mem @ W ----------------
// 128x128 tile, BK=8, 256 threads, 8x8 microtile, fp32.
// grid = (4 n-tiles, 391 m-tiles): consecutive blocks share the A-panel -> L2 hit.
__launch_bounds__(256)
__global__ void k_feat_gemm(const float* __restrict__ A0, const float* __restrict__ stoprow,
                            const float* __restrict__ B, float* __restrict__ C) {
  __shared__ float As[8][128];
  __shared__ float Bs[8][128];
  const int tid = threadIdx.x;
  const int m0 = blockIdx.y * 128, n0 = blockIdx.x * 128;
  const int tx = tid & 15, ty = tid >> 4;
  const int ar = tid >> 1, ak = (tid & 1) * 4;
  const int bk = tid >> 5, bc = (tid & 31) * 4;
  const int arow = m0 + ar;
  const float* Arow = (arow < NITEMS) ? (A0 + (size_t)arow * DD) : stoprow;
  const bool avalid = (arow < NROWS);
  float acc[8][8];
#pragma unroll
  for (int i = 0; i < 8; ++i)
#pragma unroll
    for (int j = 0; j < 8; ++j) acc[i][j] = 0.f;

  for (int kt = 0; kt < DD; kt += 8) {
    float4 av = avalid ? *(const float4*)(Arow + kt + ak) : make_float4(0.f, 0.f, 0.f, 0.f);
    As[ak + 0][ar] = av.x;
    As[ak + 1][ar] = av.y;
    As[ak + 2][ar] = av.z;
    As[ak + 3][ar] = av.w;
    *(float4*)&Bs[bk][bc] = *(const float4*)(B + (size_t)(kt + bk) * HH + n0 + bc);
    __syncthreads();
#pragma unroll
    for (int k = 0; k < 8; ++k) {
      float a[8], b[8];
      *(float4*)&a[0] = *(const float4*)&As[k][ty * 8];
      *(float4*)&a[4] = *(const float4*)&As[k][ty * 8 + 4];
      *(float4*)&b[0] = *(const float4*)&Bs[k][tx * 8];
      *(float4*)&b[4] = *(const float4*)&Bs[k][tx * 8 + 4];
#pragma unroll
      for (int i = 0; i < 8; ++i)
#pragma unroll
        for (int j = 0; j < 8; ++j) acc[i][j] = fmaf(a[i], b[j], acc[i][j]);
    }
    __syncthreads();
  }
#pragma unroll
  for (int i = 0; i < 8; ++i) {
    int row = m0 + ty * 8 + i;
    if (row < NROWS) {
      float* crow = C + (size_t)row * HH + n0 + tx * 8;
      *(float4*)crow = make_float4(acc[i][0], acc[i][1], acc[i][2], acc[i][3]);
      *(float4*)(crow + 4) = make_float4(acc[i][4], acc[i][5], acc[i][6], acc[i][7]);
    }
  }
}

// ---------------- fused LSTM step: block b computes gates i/f/g/o for index b ----------------
__launch_bounds__(256)
__global__ void k_lstm_step(const float* __restrict__ x, const float* __restrict__ hin,
                            float* __restrict__ hout, float* __restrict__ c,
                            const float* __restrict__ w_ih, const float* __restrict__ w_hh,
                            const float* __restrict__ b_ih, const float* __restrict__ b_hh) {
  __shared__ float g4[4];
  const int tid = threadIdx.x;
  const int w = tid >> 6, lane = tid & 63;
  const int b = blockIdx.x;
  const int r = w * HH + b;  // row of gate-part w
  const float4* wi = (const float4*)(w_ih + (size_t)r * DD);
  const float4* wh = (const float4*)(w_hh + (size_t)r * DD);
  const float4* x4 = (const float4*)x;
  const float4* h4 = (const float4*)hin;
  float s = 0.f;
  float4 a, ww;
  a = x4[lane * 2];     ww = wi[lane * 2];     s += a.x * ww.x + a.y * ww.y + a.z * ww.z + a.w * ww.w;
  a = x4[lane * 2 + 1]; ww = wi[lane * 2 + 1]; s += a.x * ww.x + a.y * ww.y + a.z * ww.z + a.w * ww.w;
  a = h4[lane * 2];     ww = wh[lane * 2];     s += a.x * ww.x + a.y * ww.y + a.z * ww.z + a.w * ww.w;
  a = h4[lane * 2 + 1]; ww = wh[lane * 2 + 1]; s += a.x * ww.x + a.y * ww.y + a.z * ww.z + a.w * ww.w;
#pragma unroll
  for (int off = 32; off > 0; off >>= 1) s += __shfl_xor(s, off);
  if (lane == 0) g4[w] = s + b_ih[r] + b_hh[r];
  __syncthreads();
  if (tid == 0) {
    float si = 1.f / (1.f + expf(-g4[0]));
    float sf = 1.f / (1.f + expf(-g4[1]));
    float gg = g4[2];
    float so = 1.f / (1.f + expf(-g4[3]));
    float cn = sf * c[b] + si * tanhf(gg);
    c[b] = cn;
    hout[b] = so * tanhf(cn);
  }
}

// ---------------- b[j] = sum_i q[i] * W[i][j] ----------------
__launch_bounds__(256)
__global__ void k_gemv(const float* __restrict__ q, const float* __restrict__ W,
                       float* __restrict__ out) {
  __shared__ float lds[256];
  const int tid = threadIdx.x;
  const int cc = tid & 63, rs = tid >> 6;
  const int j = blockIdx.x * 64 + cc;
  float p = 0.f;
  for (int i = rs * 128; i < rs * 128 + 128; ++i) p += q[i] * W[(size_t)i * HH + j];
  lds[tid] = p;
  __syncthreads();
  if (tid < 64) out[blockIdx.x * 64 + tid] = lds[tid] + lds[tid + 64] + lds[tid + 128] + lds[tid + 192];
}

// ---------------- fused hop: score + online-softmax weighted feat sum, one pass ----------------
// 512 blocks x 512 threads (8 waves). Block b handles rows {b + 512k}.
__launch_bounds__(512)
__global__ void k_hop_fused(const float* __restrict__ feat, const float* __restrict__ bvec,
                            const float* __restrict__ v, float* __restrict__ qp,
                            float* __restrict__ bm, float* __restrict__ bZ) {
  __shared__ float s_s[8];
  const int tid = threadIdx.x;
  const int w = tid >> 6, lane = tid & 63;
  const int b = blockIdx.x;
  float bv[8], vv[8];
#pragma unroll
  for (int j = 0; j < 8; ++j) { bv[j] = bvec[lane * 8 + j]; vv[j] = v[lane * 8 + j]; }
  float M = -3.0e38f, Z = 0.f, qa = 0.f;

  for (int ch = 0; ch < 13; ++ch) {
    const int k = ch * 8 + w;
    const int row = b + (k << 9);
    float s = -3.0e38f;
    if (row < NROWS) {
      const float4* fp = (const float4*)(feat + (size_t)row * HH);
      float4 A = fp[lane * 2], B = fp[lane * 2 + 1];
      s  = tanhf(A.x + bv[0]) * vv[0];
      s += tanhf(A.y + bv[1]) * vv[1];
      s += tanhf(A.z + bv[2]) * vv[2];
      s += tanhf(A.w + bv[3]) * vv[3];
      s += tanhf(B.x + bv[4]) * vv[4];
      s += tanhf(B.y + bv[5]) * vv[5];
      s += tanhf(B.z + bv[6]) * vv[6];
      s += tanhf(B.w + bv[7]) * vv[7];
#pragma unroll
      for (int off = 32; off > 0; off >>= 1) s += __shfl_xor(s, off);
    }
    if (lane == 0) s_s[w] = s;
    __syncthreads();
    float sv[8];
#pragma unroll
    for (int j = 0; j < 8; ++j) sv[j] = s_s[j];
    float cmax = sv[0];
#pragma unroll
    for (int j = 1; j < 8; ++j) cmax = fmaxf(cmax, sv[j]);
    const float Mn = fmaxf(M, cmax);
    const float scale = expf(M - Mn);  // M=-3e38 first time -> 0; qa,Z are 0 anyway
    qa *= scale;
    Z *= scale;
#pragma unroll
    for (int j = 0; j < 8; ++j) {
      const int rr = b + ((ch * 8 + j) << 9);
      if (rr < NROWS) {
        const float e = expf(sv[j] - Mn);
        qa = fmaf(e, feat[(size_t)rr * HH + tid], qa);
        Z += e;
      }
    }
    M = Mn;
    __syncthreads();
  }
  qp[(size_t)b * HH + tid] = qa;
  if (tid == 0) { bm[b] = M; bZ[b] = Z; }
}

// ---------------- combine hop partials -> qn ----------------
// 8 blocks x 256 threads; block j owns columns j*64..j*64+63.
__launch_bounds__(256)
__global__ void k_hop_qn(const float* __restrict__ qp, const float* __restrict__ bm,
                         const float* __restrict__ bZ, float* __restrict__ qn) {
  __shared__ float cf[512];
  __shared__ float red[256];
  const int tid = threadIdx.x;
  // global max over 512 block maxima (deterministic tree)
  red[tid] = fmaxf(bm[tid], bm[tid + 256]);
  __syncthreads();
  for (int s2 = 128; s2 > 0; s2 >>= 1) {
    if (tid < s2) red[tid] = fmaxf(red[tid], red[tid + s2]);
    __syncthreads();
  }
  const float Mg = red[0];
  __syncthreads();
  cf[tid] = expf(bm[tid] - Mg);
  cf[tid + 256] = expf(bm[tid + 256] - Mg);
  red[tid] = bZ[tid] * cf[tid] + bZ[tid + 256] * cf[tid + 256];
  __syncthreads();
  for (int s2 = 128; s2 > 0; s2 >>= 1) {
    if (tid < s2) red[tid] += red[tid + s2];
    __syncthreads();
  }
  const float Z = red[0];
  __syncthreads();
  // weighted column sums
  const int cc = tid & 63, q = tid >> 6;
  const int col = blockIdx.x * 64 + cc;
  float acc = 0.f;
  for (int bb = q * 128; bb < q * 128 + 128; ++bb)
    acc = fmaf(cf[bb], qp[(size_t)bb * HH + col], acc);
  red[tid] = acc;
  __syncthreads();
  if (tid < 64)
    qn[blockIdx.x * 64 + tid] = (red[tid] + red[tid + 64] + red[tid + 128] + red[tid + 192]) / Z;
}

// ---------------- fused attn: score + sel mask + online Z + gumbel argmax ----------------
// 512 blocks x 256 threads (4 waves); wave handles rows strided 2048.
__launch_bounds__(256)
__global__ void k_attn_fused(const float* __restrict__ feat, const float* __restrict__ bvec,
                             const float* __restrict__ v, const int* __restrict__ sel,
                             const float* __restrict__ gum, float* __restrict__ sc,
                             float* __restrict__ bm, float* __restrict__ bZ,
                             unsigned long long* __restrict__ bkey) {
  __shared__ float wm[4], wz[4];
  __shared__ unsigned long long wk[4];
  const int tid = threadIdx.x;
  const int w = tid >> 6, lane = tid & 63;
  const int wv = blockIdx.x * 4 + w;
  float bv[8], vv[8];
#pragma unroll
  for (int j = 0; j < 8; ++j) { bv[j] = bvec[lane * 8 + j]; vv[j] = v[lane * 8 + j]; }
  float M = -3.0e38f, Z = 0.f;
  unsigned long long kbest = 0ull;

  for (int m = wv; m < NROWS; m += 2048) {
    float s;
    if (sel[m]) {
      s = NEGV;
    } else {
      const float4* fp = (const float4*)(feat + (size_t)m * HH);
      float4 A = fp[lane * 2], B = fp[lane * 2 + 1];
      s  = tanhf(A.x + bv[0]) * vv[0];
      s += tanhf(A.y + bv[1]) * vv[1];
      s += tanhf(A.z + bv[2]) * vv[2];
      s += tanhf(A.w + bv[3]) * vv[3];
      s += tanhf(B.x + bv[4]) * vv[4];
      s += tanhf(B.y + bv[5]) * vv[5];
      s += tanhf(B.z + bv[6]) * vv[6];
      s += tanhf(B.w + bv[7]) * vv[7];
#pragma unroll
      for (int off = 32; off > 0; off >>= 1) s += __shfl_xor(s, off);
    }
    if (lane == 0) sc[m] = s;
    const float Mn = fmaxf(M, s);
    Z = Z * expf(M - Mn) + expf(s - Mn);
    M = Mn;
    const float svg = s + gum[m];
    const unsigned long long key =
        ((unsigned long long)fkey(svg) << 32) | (unsigned)(NITEMS - m);
    kbest = (key > kbest) ? key : kbest;
  }
  if (lane == 0) { wm[w] = M; wz[w] = Z; wk[w] = kbest; }
  __syncthreads();
  if (tid == 0) {
    float Mb = fmaxf(fmaxf(wm[0], wm[1]), fmaxf(wm[2], wm[3]));
    float Zb = wz[0] * expf(wm[0] - Mb) + wz[1] * expf(wm[1] - Mb) +
               wz[2] * expf(wm[2] - Mb) + wz[3] * expf(wm[3] - Mb);
    unsigned long long kb = wk[0];
    kb = (wk[1] > kb) ? wk[1] : kb;
    kb = (wk[2] > kb) ? wk[2] : kb;
    kb = (wk[3] > kb) ? wk[3] : kb;
    bm[blockIdx.x] = Mb;
    bZ[blockIdx.x] = Zb;
    bkey[blockIdx.x] = kb;
  }
}

// ---------------- combine attn partials, sample, bookkeeping, outputs ----------------
__launch_bounds__(512)
__global__ void k_step_final(const float* __restrict__ sc, const float* __restrict__ bm,
                             const float* __restrict__ bZ,
                             const unsigned long long* __restrict__ bkey,
                             int* __restrict__ sel, int* __restrict__ done, float* __restrict__ x,
                             const float* __restrict__ attn_mem, const float* __restrict__ stoprow,
                             float* __restrict__ outbuf, int t) {
  __shared__ float ra[512];
  __shared__ unsigned long long rk[512];
  __shared__ float s_M, s_Z;
  __shared__ int s_out, s_copy;
  const int tid = threadIdx.x;
  ra[tid] = bm[tid];
  rk[tid] = bkey[tid];
  __syncthreads();
  for (int s2 = 256; s2 > 0; s2 >>= 1) {
    if (tid < s2) {
      ra[tid] = fmaxf(ra[tid], ra[tid + s2]);
      rk[tid] = (rk[tid + s2] > rk[tid]) ? rk[tid + s2] : rk[tid];
    }
    __syncthreads();
  }
  if (tid == 0) s_M = ra[0];
  __syncthreads();
  const float M = s_M;
  ra[tid] = bZ[tid] * expf(bm[tid] - M);
  __syncthreads();
  for (int s2 = 256; s2 > 0; s2 >>= 1) {
    if (tid < s2) ra[tid] += ra[tid + s2];
    __syncthreads();
  }
  if (tid == 0) {
    const float Z = ra[0];
    const unsigned long long key = rk[0];
    const int out = NITEMS - (int)(unsigned)(key & 0xFFFFFFFFull);
    const int dn = *done;
    const float lp = dn ? 0.f : (sc[out] - M - logf(Z));
    const int orec = dn ? NITEMS : out;
    if (!dn) sel[out] = 1;
    const int nd = dn || (out == NITEMS);
    *done = nd;
    outbuf[t] = (float)orec;
    outbuf[TT + t] = lp;
    s_out = out;
    s_copy = !nd;
  }
  __syncthreads();
  if (s_copy) x[tid] = (s_out < NITEMS) ? attn_mem[(size_t)s_out * DD + tid] : stoprow[tid];
}

// ======================================================================
extern "C" void kernel_launch(void* const* d_in, const int* in_sizes, int n_in,
                              void* d_out, int out_size, void* d_ws, size_t ws_size,
                              hipStream_t stream) {
  const float* attn_mem = (const float*)d_in[0];
  const float* stoprow  = (const float*)d_in[1];
  const float* init_h   = (const float*)d_in[2];
  const float* init_c   = (const float*)d_in[3];
  const float* init_i   = (const float*)d_in[4];
  const float* attn_wm  = (const float*)d_in[5];
  const float* attn_wq  = (const float*)d_in[6];
  const float* attn_v   = (const float*)d_in[7];
  const float* hop_wm   = (const float*)d_in[8];
  const float* hop_wq   = (const float*)d_in[9];
  const float* hop_v    = (const float*)d_in[10];
  const float* w_ih     = (const float*)d_in[11];
  const float* w_hh     = (const float*)d_in[12];
  const float* b_ih     = (const float*)d_in[13];
  const float* b_hh     = (const float*)d_in[14];
  const float* gumbel   = (const float*)d_in[15];

  float* ws = (float*)d_ws;
  size_t fo = 0;
  const size_t F = (size_t)NROWS * HH;
  float* attn_feat = ws + fo; fo += F;
  float* hop_feat  = ws + fo; fo += F;
  float* sc    = ws + fo; fo += 50008;
  int*   sel   = (int*)(ws + fo); fo += 50008;
  float* qp    = ws + fo; fo += 512 * HH;
  float* bmh   = ws + fo; fo += 512;
  float* bZh   = ws + fo; fo += 512;
  float* bma   = ws + fo; fo += 512;
  float* bZa   = ws + fo; fo += 512;
  unsigned long long* bkey = (unsigned long long*)(ws + fo); fo += 1024;
  float* xv = ws + fo; fo += HH;
  float* hA = ws + fo; fo += HH;
  float* hB = ws + fo; fo += HH;
  float* cv = ws + fo; fo += HH;
  float* qn = ws + fo; fo += HH;
  float* b1 = ws + fo; fo += HH;
  float* b2 = ws + fo; fo += HH;
  int* done = (int*)(ws + fo); fo += 2;
  if (fo * sizeof(float) > ws_size) return;

  float* outf = (float*)d_out;

  k_init<<<(NROWS + 255) / 256, 256, 0, stream>>>(sel, xv, hA, cv, done, init_i, init_h, init_c);

  dim3 ggrid(4, (NROWS + 127) / 128);
  k_feat_gemm<<<ggrid, 256, 0, stream>>>(attn_mem, stoprow, attn_wm, attn_feat);
  k_feat_gemm<<<ggrid, 256, 0, stream>>>(attn_mem, stoprow, hop_wm, hop_feat);

  for (int t = 0; t < TT; ++t) {
    const float* hin = (t & 1) ? hB : hA;
    float* hout = (t & 1) ? hA : hB;
    k_lstm_step<<<HH, 256, 0, stream>>>(xv, hin, hout, cv, w_ih, w_hh, b_ih, b_hh);
    k_gemv<<<8, 256, 0, stream>>>(hout, hop_wq, b1);
    k_hop_fused<<<512, 512, 0, stream>>>(hop_feat, b1, hop_v, qp, bmh, bZh);
    k_hop_qn<<<8, 256, 0, stream>>>(qp, bmh, bZh, qn);
    k_gemv<<<8, 256, 0, stream>>>(qn, attn_wq, b2);
    k_attn_fused<<<512, 256, 0, stream>>>(attn_feat, b2, attn_v, sel,
                                          gumbel + (size_t)t * NROWS, sc, bma, bZa, bkey);
    k_step_final<<<1, 512, 0, stream>>>(sc, bma, bZa, bkey, sel, done, xv,
                                        attn_mem, stoprow, outf, t);
  }
}

// Round 3
// 3142.999 us; speedup vs baseline: 1.4874x; 1.2728x over previous
//
#include <hip/hip_runtime.h>
#include <math.h>

#define NITEMS 50000
#define NROWS 50001
#define DD 512
#define HH 512
#define TT 16
#define NEGV (-1e18f)

#define NWAVE_HOP 4096   // 1024 blocks x 4 waves
#define NBLK_ATTN 2048   // x 4 waves = 8192 waves

// ---- order-preserving float <-> uint key ----
__device__ __forceinline__ unsigned fkey(float f) {
  unsigned u = __float_as_uint(f);
  return (u & 0x80000000u) ? ~u : (u | 0x80000000u);
}

// fast tanh / exp via v_exp_f32 + v_rcp_f32 (error ~2 ulp)
__device__ __forceinline__ float ftanh(float x) {
  float e = __builtin_amdgcn_exp2f(x * 2.885390081777927f);  // exp(2x)
  return 1.f - 2.f * __builtin_amdgcn_rcpf(e + 1.f);
}
__device__ __forceinline__ float fexp(float x) {
  return __builtin_amdgcn_exp2f(x * 1.4426950408889634f);
}

// ---------------- init state ----------------
__global__ void k_init(int* __restrict__ sel, float* __restrict__ x, float* __restrict__ h,
                       float* __restrict__ c, int* __restrict__ done,
                       const float* __restrict__ init_i, const float* __restrict__ init_h,
                       const float* __restrict__ init_c) {
  int i = blockIdx.x * blockDim.x + threadIdx.x;
  if (i < NROWS) sel[i] = 0;
  if (i < HH) { x[i] = init_i[i]; h[i] = init_h[i]; c[i] = init_c[i]; }
  if (i == 0) *done = 0;
}

// ---------------- feat = mem @ W ----------------
// 128x128 tile, BK=8, 256 threads, 8x8 microtile, fp32.
// grid = (4 n-tiles, 391 m-tiles). B-fragment at {tx*4, 64+tx*4} -> 2-way LDS (free).
__launch_bounds__(256)
__global__ void k_feat_gemm(const float* __restrict__ A0, const float* __restrict__ stoprow,
                            const float* __restrict__ B, float* __restrict__ C) {
  __shared__ float As[8][128];
  __shared__ float Bs[8][128];
  const int tid = threadIdx.x;
  const int m0 = blockIdx.y * 128, n0 = blockIdx.x * 128;
  const int tx = tid & 15, ty = tid >> 4;
  const int ar = tid >> 1, ak = (tid & 1) * 4;
  const int bk = tid >> 5, bc = (tid & 31) * 4;
  const int arow = m0 + ar;
  const float* Arow = (arow < NITEMS) ? (A0 + (size_t)arow * DD) : stoprow;
  const bool avalid = (arow < NROWS);
  float acc[8][8];
#pragma unroll
  for (int i = 0; i < 8; ++i)
#pragma unroll
    for (int j = 0; j < 8; ++j) acc[i][j] = 0.f;

  for (int kt = 0; kt < DD; kt += 8) {
    float4 av = avalid ? *(const float4*)(Arow + kt + ak) : make_float4(0.f, 0.f, 0.f, 0.f);
    As[ak + 0][ar] = av.x;
    As[ak + 1][ar] = av.y;
    As[ak + 2][ar] = av.z;
    As[ak + 3][ar] = av.w;
    *(float4*)&Bs[bk][bc] = *(const float4*)(B + (size_t)(kt + bk) * HH + n0 + bc);
    __syncthreads();
#pragma unroll
    for (int k = 0; k < 8; ++k) {
      float a[8], b[8];
      *(float4*)&a[0] = *(const float4*)&As[k][ty * 8];
      *(float4*)&a[4] = *(const float4*)&As[k][ty * 8 + 4];
      *(float4*)&b[0] = *(const float4*)&Bs[k][tx * 4];
      *(float4*)&b[4] = *(const float4*)&Bs[k][64 + tx * 4];
#pragma unroll
      for (int i = 0; i < 8; ++i)
#pragma unroll
        for (int j = 0; j < 8; ++j) acc[i][j] = fmaf(a[i], b[j], acc[i][j]);
    }
    __syncthreads();
  }
#pragma unroll
  for (int i = 0; i < 8; ++i) {
    int row = m0 + ty * 8 + i;
    if (row < NROWS) {
      float* crow = C + (size_t)row * HH + n0;
      *(float4*)(crow + tx * 4) = make_float4(acc[i][0], acc[i][1], acc[i][2], acc[i][3]);
      *(float4*)(crow + 64 + tx * 4) = make_float4(acc[i][4], acc[i][5], acc[i][6], acc[i][7]);
    }
  }
}

// ---------------- fused LSTM step ----------------
__launch_bounds__(256)
__global__ void k_lstm_step(const float* __restrict__ x, const float* __restrict__ hin,
                            float* __restrict__ hout, float* __restrict__ c,
                            const float* __restrict__ w_ih, const float* __restrict__ w_hh,
                            const float* __restrict__ b_ih, const float* __restrict__ b_hh) {
  __shared__ float g4[4];
  const int tid = threadIdx.x;
  const int w = tid >> 6, lane = tid & 63;
  const int b = blockIdx.x;
  const int r = w * HH + b;
  const float4* wi = (const float4*)(w_ih + (size_t)r * DD);
  const float4* wh = (const float4*)(w_hh + (size_t)r * DD);
  const float4* x4 = (const float4*)x;
  const float4* h4 = (const float4*)hin;
  float s = 0.f;
  float4 a, ww;
  a = x4[lane * 2];     ww = wi[lane * 2];     s += a.x * ww.x + a.y * ww.y + a.z * ww.z + a.w * ww.w;
  a = x4[lane * 2 + 1]; ww = wi[lane * 2 + 1]; s += a.x * ww.x + a.y * ww.y + a.z * ww.z + a.w * ww.w;
  a = h4[lane * 2];     ww = wh[lane * 2];     s += a.x * ww.x + a.y * ww.y + a.z * ww.z + a.w * ww.w;
  a = h4[lane * 2 + 1]; ww = wh[lane * 2 + 1]; s += a.x * ww.x + a.y * ww.y + a.z * ww.z + a.w * ww.w;
#pragma unroll
  for (int off = 32; off > 0; off >>= 1) s += __shfl_xor(s, off);
  if (lane == 0) g4[w] = s + b_ih[r] + b_hh[r];
  __syncthreads();
  if (tid == 0) {
    float si = 1.f / (1.f + expf(-g4[0]));
    float sf = 1.f / (1.f + expf(-g4[1]));
    float gg = g4[2];
    float so = 1.f / (1.f + expf(-g4[3]));
    float cn = sf * c[b] + si * tanhf(gg);
    c[b] = cn;
    hout[b] = so * tanhf(cn);
  }
}

// ---------------- b[j] = sum_i q[i] * W[i][j] ----------------
__launch_bounds__(256)
__global__ void k_gemv(const float* __restrict__ q, const float* __restrict__ W,
                       float* __restrict__ out) {
  __shared__ float lds[256];
  const int tid = threadIdx.x;
  const int cc = tid & 63, rs = tid >> 6;
  const int j = blockIdx.x * 64 + cc;
  float p = 0.f;
  for (int i = rs * 128; i < rs * 128 + 128; ++i) p += q[i] * W[(size_t)i * HH + j];
  lds[tid] = p;
  __syncthreads();
  if (tid < 64) out[blockIdx.x * 64 + tid] = lds[tid] + lds[tid + 64] + lds[tid + 128] + lds[tid + 192];
}

// ---------------- hop: score + per-wave online-softmax weighted sum, ONE feat read ----------------
// 1024 blocks x 256 thr (4 waves) = 4096 waves; wave wv handles rows {wv + 4096k}.
__launch_bounds__(256)
__global__ void k_hop_fused(const float* __restrict__ feat, const float* __restrict__ bvec,
                            const float* __restrict__ v, float* __restrict__ qp,
                            float* __restrict__ bm, float* __restrict__ bZ) {
  const int tid = threadIdx.x;
  const int w = tid >> 6, lane = tid & 63;
  const int wv = blockIdx.x * 4 + w;
  float bv[8], vv[8], qa[8];
#pragma unroll
  for (int j = 0; j < 8; ++j) { bv[j] = bvec[lane * 8 + j]; vv[j] = v[lane * 8 + j]; qa[j] = 0.f; }
  float M = -3.0e38f, Z = 0.f;
  for (int m = wv; m < NROWS; m += NWAVE_HOP) {
    const float4* fp = (const float4*)(feat + (size_t)m * HH);
    float4 A = fp[lane * 2], B = fp[lane * 2 + 1];
    float f[8] = {A.x, A.y, A.z, A.w, B.x, B.y, B.z, B.w};
    float s = 0.f;
#pragma unroll
    for (int j = 0; j < 8; ++j) s += ftanh(f[j] + bv[j]) * vv[j];
#pragma unroll
    for (int off = 32; off > 0; off >>= 1) s += __shfl_xor(s, off);
    const float Mn = fmaxf(M, s);
    const float scale = fexp(M - Mn);
    const float e = fexp(s - Mn);
    Z = Z * scale + e;
#pragma unroll
    for (int j = 0; j < 8; ++j) qa[j] = fmaf(e, f[j], qa[j] * scale);
    M = Mn;
  }
  float4* qpo = (float4*)(qp + (size_t)wv * HH + lane * 8);
  qpo[0] = make_float4(qa[0], qa[1], qa[2], qa[3]);
  qpo[1] = make_float4(qa[4], qa[5], qa[6], qa[7]);
  if (lane == 0) { bm[wv] = M; bZ[wv] = Z; }
}

// ---------------- combine hop partials -> qn.  16 blocks x 1024 thr; block owns 32 cols ----------------
__launch_bounds__(1024)
__global__ void k_hop_qn(const float* __restrict__ qp, const float* __restrict__ bm,
                         const float* __restrict__ bZ, float* __restrict__ qn) {
  __shared__ float red[1024];
  __shared__ float cf[NWAVE_HOP];
  const int tid = threadIdx.x;
  float m0 = fmaxf(fmaxf(bm[tid], bm[tid + 1024]), fmaxf(bm[tid + 2048], bm[tid + 3072]));
  red[tid] = m0;
  __syncthreads();
  for (int s2 = 512; s2 > 0; s2 >>= 1) {
    if (tid < s2) red[tid] = fmaxf(red[tid], red[tid + s2]);
    __syncthreads();
  }
  const float Mg = red[0];
  __syncthreads();
  float zz = 0.f;
#pragma unroll
  for (int j = 0; j < 4; ++j) {
    float cc = expf(bm[tid + 1024 * j] - Mg);
    cf[tid + 1024 * j] = cc;
    zz += bZ[tid + 1024 * j] * cc;
  }
  red[tid] = zz;
  __syncthreads();
  for (int s2 = 512; s2 > 0; s2 >>= 1) {
    if (tid < s2) red[tid] += red[tid + s2];
    __syncthreads();
  }
  const float Z = red[0];
  __syncthreads();
  const int cc = tid & 31, q = tid >> 5;  // q: 0..31
  const int col = blockIdx.x * 32 + cc;
  float acc = 0.f;
  for (int p = q * 128; p < q * 128 + 128; ++p) acc = fmaf(cf[p], qp[(size_t)p * HH + col], acc);
  red[tid] = acc;
  __syncthreads();
  if (tid < 32) {
    float a = 0.f;
#pragma unroll
    for (int g = 0; g < 32; ++g) a += red[tid + 32 * g];
    qn[blockIdx.x * 32 + tid] = a / Z;
  }
}

// ---------------- attn: score + sel mask + online Z + gumbel argmax ----------------
// 2048 blocks x 256 thr (4 waves) = 8192 waves; wave wv handles rows {wv + 8192k}.
__launch_bounds__(256)
__global__ void k_attn_fused(const float* __restrict__ feat, const float* __restrict__ bvec,
                             const float* __restrict__ v, const int* __restrict__ sel,
                             const float* __restrict__ gum, float* __restrict__ sc,
                             float* __restrict__ bm, float* __restrict__ bZ,
                             unsigned long long* __restrict__ bkey) {
  __shared__ float wm[4], wz[4];
  __shared__ unsigned long long wk[4];
  const int tid = threadIdx.x;
  const int w = tid >> 6, lane = tid & 63;
  const int wv = blockIdx.x * 4 + w;
  float bv[8], vv[8];
#pragma unroll
  for (int j = 0; j < 8; ++j) { bv[j] = bvec[lane * 8 + j]; vv[j] = v[lane * 8 + j]; }
  float M = -3.0e38f, Z = 0.f;
  unsigned long long kbest = 0ull;

  for (int m = wv; m < NROWS; m += 4 * NBLK_ATTN) {
    float s;
    if (sel[m]) {
      s = NEGV;
    } else {
      const float4* fp = (const float4*)(feat + (size_t)m * HH);
      float4 A = fp[lane * 2], B = fp[lane * 2 + 1];
      s  = ftanh(A.x + bv[0]) * vv[0];
      s += ftanh(A.y + bv[1]) * vv[1];
      s += ftanh(A.z + bv[2]) * vv[2];
      s += ftanh(A.w + bv[3]) * vv[3];
      s += ftanh(B.x + bv[4]) * vv[4];
      s += ftanh(B.y + bv[5]) * vv[5];
      s += ftanh(B.z + bv[6]) * vv[6];
      s += ftanh(B.w + bv[7]) * vv[7];
#pragma unroll
      for (int off = 32; off > 0; off >>= 1) s += __shfl_xor(s, off);
    }
    if (lane == 0) sc[m] = s;
    const float Mn = fmaxf(M, s);
    Z = Z * fexp(M - Mn) + fexp(s - Mn);
    M = Mn;
    const float svg = s + gum[m];
    const unsigned long long key =
        ((unsigned long long)fkey(svg) << 32) | (unsigned)(NITEMS - m);
    kbest = (key > kbest) ? key : kbest;
  }
  if (lane == 0) { wm[w] = M; wz[w] = Z; wk[w] = kbest; }
  __syncthreads();
  if (tid == 0) {
    float Mb = fmaxf(fmaxf(wm[0], wm[1]), fmaxf(wm[2], wm[3]));
    float Zb = wz[0] * expf(wm[0] - Mb) + wz[1] * expf(wm[1] - Mb) +
               wz[2] * expf(wm[2] - Mb) + wz[3] * expf(wm[3] - Mb);
    unsigned long long kb = wk[0];
    kb = (wk[1] > kb) ? wk[1] : kb;
    kb = (wk[2] > kb) ? wk[2] : kb;
    kb = (wk[3] > kb) ? wk[3] : kb;
    bm[blockIdx.x] = Mb;
    bZ[blockIdx.x] = Zb;
    bkey[blockIdx.x] = kb;
  }
}

// ---------------- combine attn partials (2048), sample, bookkeeping, outputs ----------------
__launch_bounds__(512)
__global__ void k_step_final(const float* __restrict__ sc, const float* __restrict__ bm,
                             const float* __restrict__ bZ,
                             const unsigned long long* __restrict__ bkey,
                             int* __restrict__ sel, int* __restrict__ done, float* __restrict__ x,
                             const float* __restrict__ attn_mem, const float* __restrict__ stoprow,
                             float* __restrict__ outbuf, int t) {
  __shared__ float ra[512];
  __shared__ unsigned long long rk[512];
  __shared__ float s_M;
  __shared__ int s_out, s_copy;
  const int tid = threadIdx.x;
  float m0 = fmaxf(fmaxf(bm[tid], bm[tid + 512]), fmaxf(bm[tid + 1024], bm[tid + 1536]));
  unsigned long long k0 = bkey[tid], k1 = bkey[tid + 512], k2 = bkey[tid + 1024], k3 = bkey[tid + 1536];
  k0 = (k1 > k0) ? k1 : k0;
  k2 = (k3 > k2) ? k3 : k2;
  ra[tid] = m0;
  rk[tid] = (k2 > k0) ? k2 : k0;
  __syncthreads();
  for (int s2 = 256; s2 > 0; s2 >>= 1) {
    if (tid < s2) {
      ra[tid] = fmaxf(ra[tid], ra[tid + s2]);
      rk[tid] = (rk[tid + s2] > rk[tid]) ? rk[tid + s2] : rk[tid];
    }
    __syncthreads();
  }
  if (tid == 0) s_M = ra[0];
  __syncthreads();
  const float M = s_M;
  float zz = 0.f;
#pragma unroll
  for (int j = 0; j < 4; ++j) zz += bZ[tid + 512 * j] * expf(bm[tid + 512 * j] - M);
  ra[tid] = zz;
  __syncthreads();
  for (int s2 = 256; s2 > 0; s2 >>= 1) {
    if (tid < s2) ra[tid] += ra[tid + s2];
    __syncthreads();
  }
  if (tid == 0) {
    const float Z = ra[0];
    const unsigned long long key = rk[0];
    const int out = NITEMS - (int)(unsigned)(key & 0xFFFFFFFFull);
    const int dn = *done;
    const float lp = dn ? 0.f : (sc[out] - M - logf(Z));
    const int orec = dn ? NITEMS : out;
    if (!dn) sel[out] = 1;
    const int nd = dn || (out == NITEMS);
    *done = nd;
    outbuf[t] = (float)orec;
    outbuf[TT + t] = lp;
    s_out = out;
    s_copy = !nd;
  }
  __syncthreads();
  if (s_copy) x[tid] = (s_out < NITEMS) ? attn_mem[(size_t)s_out * DD + tid] : stoprow[tid];
}

// ======================================================================
extern "C" void kernel_launch(void* const* d_in, const int* in_sizes, int n_in,
                              void* d_out, int out_size, void* d_ws, size_t ws_size,
                              hipStream_t stream) {
  const float* attn_mem = (const float*)d_in[0];
  const float* stoprow  = (const float*)d_in[1];
  const float* init_h   = (const float*)d_in[2];
  const float* init_c   = (const float*)d_in[3];
  const float* init_i   = (const float*)d_in[4];
  const float* attn_wm  = (const float*)d_in[5];
  const float* attn_wq  = (const float*)d_in[6];
  const float* attn_v   = (const float*)d_in[7];
  const float* hop_wm   = (const float*)d_in[8];
  const float* hop_wq   = (const float*)d_in[9];
  const float* hop_v    = (const float*)d_in[10];
  const float* w_ih     = (const float*)d_in[11];
  const float* w_hh     = (const float*)d_in[12];
  const float* b_ih     = (const float*)d_in[13];
  const float* b_hh     = (const float*)d_in[14];
  const float* gumbel   = (const float*)d_in[15];

  float* ws = (float*)d_ws;
  size_t fo = 0;
  const size_t F = (size_t)NROWS * HH;
  float* attn_feat = ws + fo; fo += F;
  float* hop_feat  = ws + fo; fo += F;
  float* sc    = ws + fo; fo += 50008;
  int*   sel   = (int*)(ws + fo); fo += 50008;
  float* qp    = ws + fo; fo += (size_t)NWAVE_HOP * HH;
  float* bmh   = ws + fo; fo += NWAVE_HOP;
  float* bZh   = ws + fo; fo += NWAVE_HOP;
  float* bma   = ws + fo; fo += NBLK_ATTN;
  float* bZa   = ws + fo; fo += NBLK_ATTN;
  unsigned long long* bkey = (unsigned long long*)(ws + fo); fo += 2 * NBLK_ATTN;
  float* xv = ws + fo; fo += HH;
  float* hA = ws + fo; fo += HH;
  float* hB = ws + fo; fo += HH;
  float* cv = ws + fo; fo += HH;
  float* qn = ws + fo; fo += HH;
  float* b1 = ws + fo; fo += HH;
  float* b2 = ws + fo; fo += HH;
  int* done = (int*)(ws + fo); fo += 2;
  if (fo * sizeof(float) > ws_size) return;

  float* outf = (float*)d_out;

  k_init<<<(NROWS + 255) / 256, 256, 0, stream>>>(sel, xv, hA, cv, done, init_i, init_h, init_c);

  dim3 ggrid(4, (NROWS + 127) / 128);
  k_feat_gemm<<<ggrid, 256, 0, stream>>>(attn_mem, stoprow, attn_wm, attn_feat);
  k_feat_gemm<<<ggrid, 256, 0, stream>>>(attn_mem, stoprow, hop_wm, hop_feat);

  for (int t = 0; t < TT; ++t) {
    const float* hin = (t & 1) ? hB : hA;
    float* hout = (t & 1) ? hA : hB;
    k_lstm_step<<<HH, 256, 0, stream>>>(xv, hin, hout, cv, w_ih, w_hh, b_ih, b_hh);
    k_gemv<<<8, 256, 0, stream>>>(hout, hop_wq, b1);
    k_hop_fused<<<NWAVE_HOP / 4, 256, 0, stream>>>(hop_feat, b1, hop_v, qp, bmh, bZh);
    k_hop_qn<<<16, 1024, 0, stream>>>(qp, bmh, bZh, qn);
    k_gemv<<<8, 256, 0, stream>>>(qn, attn_wq, b2);
    k_attn_fused<<<NBLK_ATTN, 256, 0, stream>>>(attn_feat, b2, attn_v, sel,
                                                gumbel + (size_t)t * NROWS, sc, bma, bZa, bkey);
    k_step_final<<<1, 512, 0, stream>>>(sc, bma, bZa, bkey, sel, done, xv,
                                        attn_mem, stoprow, outf, t);
  }
}